// Round 4
// baseline (179.586 us; speedup 1.0000x reference)
//
#include <hip/hip_runtime.h>
#include <hip/hip_bf16.h>

// GCN layer: out = relu( D^-1/2 (dedup(A) + I) D^-1/2 (X @ W) )
// N=10000, E=320000, F=256.
// Storage: fp32 X/W/out (PROVEN r9/r10: removing fp32 paths -> NaN->relu->0;
// restoring them passes at 1 bf16 ulp). Edges: int32 expected, int64 tolerated
// via per-wave ballot detect (no flags buffer, no sync).
// Strategy: bf16-cast W once (Wt, transposed); GEMM reads fp32 X directly and
// converts A-fragments in-register (no Xb buffer, no cast pass).
// r1 lesson: zero returning atomics.
// r3 post-mortem: 320k scattered device-scope atomicOr over a 12.5 MB global
// bitmap cost ~45-50 us REGARDLESS of chain structure (r1 chain 51us, r3
// fire-and-forget 49us; MfmaUtil/VALUBusy ~1%, HBM 452 GB/s of random-line
// RMW churn on lines left dirty across 8 non-coherent XCD L2s by the zeroing
// pass). THIS ROUND: no global bitmap at all. 200 blocks x 512 thr; each
// block owns a 50-node slice with a PRIVATE LDS bitmap (50 x 320 words =
// 64,000 B), streams the source-id array (target quad loaded lazily on slice
// hit, ~0.5%), dedups via fast LDS atomicOr (ds_or), then popcount+shfl-
// prefix scans its own bitmap in place -> adj/cnt, deg[t]++ fire-and-forget
// (dense 40KB target, proven cheap in r2/r3 k_scan). Deletes: 12.8MB bitmap
// zero, 320k global atomics, 12.8MB bitmap re-read, one launch.
// 3 launches: k_pre(deg init + Wt) -> k_fillscan_gemm -> k_gather.
// r8 lesson: no cooperative mega-kernel. r6 lesson: GEMM merge only at BLOCK
// level (thread-level merge = 30x regalloc blowup; r3 proved block-level is
// safe, VGPR 64).
//
// ws layout (bytes), ~9.2 MB (ws is 256 MiB per harness poison fill):
//   deg   i32[N]       @ 0           (distinct in-degree + 1 self)
//   cnt   i32[N]       @ 40,960      (deduped out-degree)
//   adj   i32[N*96]    @ 81,920      (fixed-stride adjacency, deduped)
//   Wt    bf16[F*F]    @ 3,921,920   (W cast+transposed: Wt[n][k])
//   H     bf16[N*F]    @ 4,052,992   (bf16(X) @ bf16(W))

constexpr int N = 10000;
constexpr int E = 320000;
constexpr int F = 256;
constexpr int DEGCAP = 96;   // Poisson(32): P(any deduped degree >= 96) ~ 1e-16
constexpr int SLICE = 50;    // nodes per fillscan block (200 blocks exactly)
constexpr int BMWW  = 320;   // LDS bitmap words per row (10240 bits >= N)

constexpr size_t OFF_DEG = 0;
constexpr size_t OFF_CNT = 40960;
constexpr size_t OFF_ADJ = 81920;
constexpr size_t OFF_WT  = OFF_ADJ + 4ull * N * DEGCAP;  // 3,921,920
constexpr size_t OFF_H   = OFF_WT + 2ull * F * F;        // 4,052,992

constexpr int FS_BLKS   = N / SLICE;            // 200 fillscan blocks
constexpr int GEMM_BLKS = (N / 16 + 7) / 8;     // 79 blocks x 8 strips (625 used)

typedef short s8v __attribute__((ext_vector_type(8)));   // 8 bf16 = 4 VGPRs
typedef float f4v __attribute__((ext_vector_type(4)));   // MFMA accumulator

__device__ __forceinline__ float bf2f(unsigned short u) {
    union { unsigned u; float f; } c; c.u = (unsigned)u << 16; return c.f;
}
__device__ __forceinline__ unsigned short f2bf(float f) {
    union { __hip_bfloat16 b; unsigned short s; } c; c.b = __float2bfloat16(f); return c.s;
}

// 64 blocks: deg=1 (+I self-loop); W (fp32) -> Wt (bf16, transposed).
// cnt needs no init (k_fillscan writes every entry). No bitmap to zero.
__global__ void k_pre(int* __restrict__ deg,
                      const float* __restrict__ W, unsigned short* __restrict__ Wt) {
    __shared__ unsigned short ls[4][F];
    int i = blockIdx.x * blockDim.x + threadIdx.x;
    if (i < N) deg[i] = 1;

    int n0 = blockIdx.x * 4;  // this block owns W cols n0..n0+3 (Wt rows)
    int k = threadIdx.x;
    float4 v = *(const float4*)&W[k * F + n0];
    ls[0][k] = f2bf(v.x); ls[1][k] = f2bf(v.y);
    ls[2][k] = f2bf(v.z); ls[3][k] = f2bf(v.w);
    __syncthreads();
    int nn = threadIdx.x >> 6;
    int kk = (threadIdx.x & 63) * 4;
    uint2 o;
    o.x = (unsigned)ls[nn][kk]     | ((unsigned)ls[nn][kk + 1] << 16);
    o.y = (unsigned)ls[nn][kk + 2] | ((unsigned)ls[nn][kk + 3] << 16);
    *(uint2*)&Wt[(n0 + nn) * F + kk] = o;
}

// Fused LDS-bitmap fill+scan (blocks 0..199) + GEMM (blocks 200..278).
// Fill+scan path: block b owns sources [b*50, b*50+50). LDS bitmap
// 50x320 words. Stream source quads; on slice hit (rare) load target quad
// lazily and ds_or the bit. Then scan own bitmap: popcount + wave prefix
// (shfl) -> exact adj offsets and cnt (NO cnt atomics); deg[t]++
// fire-and-forget (dense). Words 313..319 never set (t < 10000).
// GEMM path: H = bf16(X) @ bf16(W) via MFMA 16x16x32, one wave per 16-row
// strip (8 strips/block). A-frag: X fp32 read directly (2x float4), bf16
// convert in-register. B-frag: Wt (L2-resident). C layout: col = lane&15,
// row = (lane>>4)*4 + reg  [learn_hip m89/m91].
__global__ void __launch_bounds__(512) k_fillscan_gemm(
    const int* __restrict__ edges,
    int* __restrict__ adj, int* __restrict__ cnt, int* __restrict__ deg,
    const float* __restrict__ X, const unsigned short* __restrict__ Wt,
    unsigned short* __restrict__ H) {
    __shared__ unsigned bmp[SLICE][BMWW];  // 64,000 B
    int tid = threadIdx.x;

    if (blockIdx.x >= FS_BLKS) {
        // --- GEMM path (no __syncthreads; LDS unused) ---
        int strip = (blockIdx.x - FS_BLKS) * 8 + (tid >> 6);
        if (strip >= N / 16) return;
        int lane = tid & 63;
        int r0 = strip * 16;
        int m = lane & 15, q = lane >> 4;
        const float4* A = (const float4*)(X + (r0 + m) * F + q * 8);
        const s8v* B = (const s8v*)(Wt + m * F + q * 8);
        f4v acc[16] = {};
#pragma unroll
        for (int kk = 0; kk < 8; ++kk) {
            float4 u = A[kk * 8];
            float4 v = A[kk * 8 + 1];
            s8v af;
            af[0] = (short)f2bf(u.x); af[1] = (short)f2bf(u.y);
            af[2] = (short)f2bf(u.z); af[3] = (short)f2bf(u.w);
            af[4] = (short)f2bf(v.x); af[5] = (short)f2bf(v.y);
            af[6] = (short)f2bf(v.z); af[7] = (short)f2bf(v.w);
#pragma unroll
            for (int t = 0; t < 16; ++t) {
                s8v bf = B[t * 512 + kk * 4];
                acc[t] = __builtin_amdgcn_mfma_f32_16x16x32_bf16(af, bf, acc[t], 0, 0, 0);
            }
        }
#pragma unroll
        for (int t = 0; t < 16; ++t) {
            int col = t * 16 + m;
#pragma unroll
            for (int i = 0; i < 4; ++i)
                H[(r0 + q * 4 + i) * F + col] = f2bf(acc[t][i]);
        }
        return;
    }

    // --- fill+scan path ---
    // Edge dtype probe (wave-local ballot, before barrier): int32 storage ->
    // odd words are node ids (nonzero w.p. 1-1e-4 each); int64 -> high
    // halves == 0 (ids < 1e4).
    int probe = edges[2 * (tid & 63) + 1];
    bool is32 = __ballot(probe != 0) != 0ull;

    {   // zero LDS bitmap: 4000 uint4 / 512 threads = 8 iters
        uint4 z; z.x = 0u; z.y = 0u; z.z = 0u; z.w = 0u;
        uint4* z4 = (uint4*)&bmp[0][0];
        for (int i = tid; i < SLICE * BMWW / 4; i += 512) z4[i] = z;
    }
    __syncthreads();

    int s0 = blockIdx.x * SLICE;
    const uint4* E4 = (const uint4*)edges;
    if (is32) {
        // sources = words [0,E) = quads [0,E/4); targets = quads [E/4, E/2)
#pragma unroll 4
        for (int i = tid; i < E / 4; i += 512) {
            uint4 sv = E4[i];
            int a0 = (int)sv.x - s0, a1 = (int)sv.y - s0;
            int a2 = (int)sv.z - s0, a3 = (int)sv.w - s0;
            bool h0 = (unsigned)a0 < (unsigned)SLICE;
            bool h1 = (unsigned)a1 < (unsigned)SLICE;
            bool h2 = (unsigned)a2 < (unsigned)SLICE;
            bool h3 = (unsigned)a3 < (unsigned)SLICE;
            if (h0 | h1 | h2 | h3) {  // lazy target load, ~0.5% of lanes
                uint4 tv = E4[E / 4 + i];
                if (h0 && tv.x < (unsigned)N) atomicOr(&bmp[a0][tv.x >> 5], 1u << (tv.x & 31));
                if (h1 && tv.y < (unsigned)N) atomicOr(&bmp[a1][tv.y >> 5], 1u << (tv.y & 31));
                if (h2 && tv.z < (unsigned)N) atomicOr(&bmp[a2][tv.z >> 5], 1u << (tv.z & 31));
                if (h3 && tv.w < (unsigned)N) atomicOr(&bmp[a3][tv.w >> 5], 1u << (tv.w & 31));
            }
        }
    } else {
        // int64: sources = quads [0, E/2) (lo at .x/.z); targets = quads
        // [E/2, E) (lo at .x/.z). High halves 0 for valid ids.
#pragma unroll 4
        for (int i = tid; i < E / 2; i += 512) {
            uint4 sv = E4[i];
            int a0 = (int)sv.x - s0, a1 = (int)sv.z - s0;
            bool h0 = (unsigned)a0 < (unsigned)SLICE;
            bool h1 = (unsigned)a1 < (unsigned)SLICE;
            if (h0 | h1) {
                uint4 tv = E4[E / 2 + i];
                if (h0 && tv.x < (unsigned)N) atomicOr(&bmp[a0][tv.x >> 5], 1u << (tv.x & 31));
                if (h1 && tv.z < (unsigned)N) atomicOr(&bmp[a1][tv.z >> 5], 1u << (tv.z & 31));
            }
        }
    }
    __syncthreads();

    // scan own bitmap: 8 waves, rows r = wave, wave+8, ... (50 rows)
    int wave = tid >> 6, lane = tid & 63;
    for (int r = wave; r < SLICE; r += 8) {
        int s = s0 + r;
        const unsigned* row = bmp[r];
        unsigned w0 = row[lane];
        unsigned w1 = row[lane + 64];
        unsigned w2 = row[lane + 128];
        unsigned w3 = row[lane + 192];
        unsigned w4 = row[lane + 256];
        int pc = __popc(w0) + __popc(w1) + __popc(w2) + __popc(w3) + __popc(w4);
        int sc = pc;
#pragma unroll
        for (int d = 1; d < 64; d <<= 1) {
            int v = __shfl_up(sc, d);
            if (lane >= d) sc += v;
        }
        int o = sc - pc;  // exclusive prefix = this lane's first adj slot
        if (lane == 63) cnt[s] = sc < DEGCAP ? sc : DEGCAP;
        int* arow = adj + s * DEGCAP;
        unsigned wv[5] = {w0, w1, w2, w3, w4};
#pragma unroll
        for (int j = 0; j < 5; ++j) {
            unsigned w = wv[j];
            int base = (j * 64 + lane) * 32;
            while (w) {
                int b = __ffs(w) - 1;
                w &= w - 1;
                int t = base + b;
                if (o < DEGCAP) arow[o] = t;
                ++o;
                atomicAdd(&deg[t], 1);  // fire-and-forget, dense 40KB target
            }
        }
    }
}

#define ACC8(hv, dv)                                          \
    p0 += dv * bf2f((unsigned short)(hv.x & 0xFFFF));         \
    p1 += dv * bf2f((unsigned short)(hv.x >> 16));            \
    p2 += dv * bf2f((unsigned short)(hv.y & 0xFFFF));         \
    p3 += dv * bf2f((unsigned short)(hv.y >> 16));            \
    p4 += dv * bf2f((unsigned short)(hv.z & 0xFFFF));         \
    p5 += dv * bf2f((unsigned short)(hv.z >> 16));            \
    p6 += dv * bf2f((unsigned short)(hv.w & 0xFFFF));         \
    p7 += dv * bf2f((unsigned short)(hv.w >> 16));

// r7/r10-proven gather, fp32 output. One wave per node, half-wave neighbor
// pairing: lanes 0-31 even neighbors, 32-63 odd; 16B loads (8 feats), 4 rows
// in flight. Neighbor ids/dinv register-cached, shfl-broadcast (lanes >= c
// give d=0 padding). shfl-xor-32 reduction, fused norm + self-loop + ReLU.
__global__ void k_gather(const int* __restrict__ adj, const int* __restrict__ cnt,
                         const int* __restrict__ deg,
                         const unsigned short* __restrict__ H,
                         float* __restrict__ out) {
    int wave = threadIdx.x >> 6;
    int lane = threadIdx.x & 63;
    int s = blockIdx.x * 4 + wave;  // N = 2500*4 exactly
    int half = lane >> 5, hl = lane & 31;
    const uint4* H16 = (const uint4*)H;  // 8 bf16 per uint4; row stride 32
    float ds = rsqrtf((float)deg[s]);
    int c = cnt[s]; if (c > DEGCAP) c = DEGCAP;
    const int* a = adj + s * DEGCAP;
    int tl = 0; float dl = 0.0f;
    if (lane < c) { tl = a[lane]; dl = rsqrtf((float)deg[tl]); }

    uint4 hs = H16[s * 32 + hl];
    float p0, p1, p2, p3, p4, p5, p6, p7;
    {
        float w = half ? 0.0f : ds;  // self term once (half 0 only)
        p0 = w * bf2f((unsigned short)(hs.x & 0xFFFF));
        p1 = w * bf2f((unsigned short)(hs.x >> 16));
        p2 = w * bf2f((unsigned short)(hs.y & 0xFFFF));
        p3 = w * bf2f((unsigned short)(hs.y >> 16));
        p4 = w * bf2f((unsigned short)(hs.z & 0xFFFF));
        p5 = w * bf2f((unsigned short)(hs.z >> 16));
        p6 = w * bf2f((unsigned short)(hs.w & 0xFFFF));
        p7 = w * bf2f((unsigned short)(hs.w >> 16));
    }
    int cc = c < 64 ? c : 64;
    for (int i = 0; i < cc; i += 8) {  // 4 pairs = 8 neighbors per iter
        int i0 = i + half, i1 = i + 2 + half, i2 = i + 4 + half, i3 = i + 6 + half;
        int t0 = __shfl(tl, i0), t1 = __shfl(tl, i1);
        int t2 = __shfl(tl, i2), t3 = __shfl(tl, i3);
        float d0 = __shfl(dl, i0), d1 = __shfl(dl, i1);
        float d2 = __shfl(dl, i2), d3 = __shfl(dl, i3);
        uint4 h0 = H16[t0 * 32 + hl];
        uint4 h1 = H16[t1 * 32 + hl];
        uint4 h2 = H16[t2 * 32 + hl];
        uint4 h3 = H16[t3 * 32 + hl];
        ACC8(h0, d0) ACC8(h1, d1) ACC8(h2, d2) ACC8(h3, d3)
    }
    for (int i = 64; i < c; ++i) {  // rare: deduped degree > 64
        int t = a[i];
        float d = half ? 0.0f : rsqrtf((float)deg[t]);
        uint4 h = H16[t * 32 + hl];
        ACC8(h, d)
    }
    p0 += __shfl(p0, lane ^ 32); p1 += __shfl(p1, lane ^ 32);
    p2 += __shfl(p2, lane ^ 32); p3 += __shfl(p3, lane ^ 32);
    p4 += __shfl(p4, lane ^ 32); p5 += __shfl(p5, lane ^ 32);
    p6 += __shfl(p6, lane ^ 32); p7 += __shfl(p7, lane ^ 32);
    p0 = fmaxf(p0 * ds, 0.0f); p1 = fmaxf(p1 * ds, 0.0f);
    p2 = fmaxf(p2 * ds, 0.0f); p3 = fmaxf(p3 * ds, 0.0f);
    p4 = fmaxf(p4 * ds, 0.0f); p5 = fmaxf(p5 * ds, 0.0f);
    p6 = fmaxf(p6 * ds, 0.0f); p7 = fmaxf(p7 * ds, 0.0f);
    float4 o;
    if (half) { o.x = p4; o.y = p5; o.z = p6; o.w = p7; }
    else      { o.x = p0; o.y = p1; o.z = p2; o.w = p3; }
    ((float4*)out)[s * 64 + hl * 2 + half] = o;
}

extern "C" void kernel_launch(void* const* d_in, const int* in_sizes, int n_in,
                              void* d_out, int out_size, void* d_ws, size_t ws_size,
                              hipStream_t stream) {
    const float* X = (const float*)d_in[0];
    const float* W = (const float*)d_in[1];
    const int* edges = (const int*)d_in[2];

    char* ws = (char*)d_ws;
    int* deg           = (int*)(ws + OFF_DEG);
    int* cnt           = (int*)(ws + OFF_CNT);
    int* adj           = (int*)(ws + OFF_ADJ);
    unsigned short* Wt = (unsigned short*)(ws + OFF_WT);
    unsigned short* H  = (unsigned short*)(ws + OFF_H);

    k_pre<<<64, 256, 0, stream>>>(deg, W, Wt);
    k_fillscan_gemm<<<FS_BLKS + GEMM_BLKS, 512, 0, stream>>>(edges, adj, cnt, deg, X, Wt, H);
    k_gather<<<N / 4, 256, 0, stream>>>(adj, cnt, deg, H, (float*)d_out);
}

// Round 7
// 168.697 us; speedup vs baseline: 1.0645x; 1.0645x over previous
//
#include <hip/hip_runtime.h>
#include <hip/hip_bf16.h>

// GCN layer: out = relu( D^-1/2 (dedup(A) + I) D^-1/2 (X @ W) )
// N=10000, E=320000, F=256.
// Storage: fp32 X/W/out (PROVEN r9/r10). Edges: int32 expected, int64
// tolerated via per-wave ballot detect.
// Cost model (established r1-r4): ~630k device-scope atomics at ~130ns
// effective each were ~80us of the 150us total: 320k atomicOr (fill) on
// bitmap lines left DIRTY in writer XCDs' L2s by the zeroing pass, and
// 310k atomicAdd(deg) ping-ponging 640 lines across 8 XCDs. r4's LDS
// fillscan regressed (dependent lazy-load chain, 2 blocks/CU LDS cap).
// THIS ROUND (r6 = compile fix: NT store needs native clang ext_vector,
// not HIP_vector_type uint4; theory unchanged from r4/r5):
// (1) zero bitmap with NON-TEMPORAL stores -> no dirty L2 lines -> fill
// atomics RMW clean memory-side lines (no cross-XCD ownership dance).
// (2) ZERO global deg atomics: k_scan uses a private per-block LDS
// histogram (ds_add) over 64-row strips, flushed non-atomically to
// part[157][N]; k_deg reduces partials coalesced.
// 5 launches: k_pre(Wt + NT bitmap zero) -> k_fill_gemm (r3-proven fused,
// block-level split) -> k_scan(adj/cnt + LDS hist) -> k_deg -> k_gather.
// r8: no cooperative mega-kernel. r6: GEMM merge only at BLOCK level.
//
// ws layout (bytes), ~28.3 MB (ws is 256 MiB):
//   deg   i32[N]        @ 0
//   cnt   i32[N]        @ 40,960
//   adj   i32[N*96]     @ 81,920
//   Wt    bf16[F*F]     @ 3,921,920
//   H     bf16[N*F]     @ 4,052,992
//   bm    u32[N*320]    @ 9,172,992    (12.8 MB dedup bitmap)
//   part  i32[157*N]    @ 21,972,992   (6.28 MB deg partial histograms)

constexpr int N = 10000;
constexpr int E = 320000;
constexpr int F = 256;
constexpr int DEGCAP = 96;   // Poisson(32): P(any deduped degree >= 96) ~ 1e-16
constexpr int BMW = 320;     // bitmap words per row (10240 bits >= N)
constexpr int SROWS = 64;    // rows per scan block
constexpr int SBLKS = (N + SROWS - 1) / SROWS;  // 157

constexpr size_t OFF_DEG  = 0;
constexpr size_t OFF_CNT  = 40960;
constexpr size_t OFF_ADJ  = 81920;
constexpr size_t OFF_WT   = OFF_ADJ + 4ull * N * DEGCAP;   // 3,921,920
constexpr size_t OFF_H    = OFF_WT + 2ull * F * F;         // 4,052,992
constexpr size_t OFF_BM   = OFF_H + 2ull * N * F;          // 9,172,992
constexpr size_t OFF_PART = OFF_BM + 4ull * N * BMW;       // 21,972,992
constexpr int BM_U4 = N * BMW / 4;                         // 800,000

constexpr int FILL_BLKS = (E + 255) / 256;               // 1250
constexpr int GEMM_BLKS = (N / 16 + 3) / 4;              // 157 (628 strips, 625 used)

typedef short s8v __attribute__((ext_vector_type(8)));   // 8 bf16 = 4 VGPRs
typedef float f4v __attribute__((ext_vector_type(4)));   // MFMA accumulator
typedef unsigned u4v __attribute__((ext_vector_type(4)));  // native vec for NT store

__device__ __forceinline__ float bf2f(unsigned short u) {
    union { unsigned u; float f; } c; c.u = (unsigned)u << 16; return c.f;
}
__device__ __forceinline__ unsigned short f2bf(float f) {
    union { __hip_bfloat16 b; unsigned short s; } c; c.b = __float2bfloat16(f); return c.s;
}

// 256 blocks: zero dedup bitmap with NON-TEMPORAL 16B stores (lines must
// not be left dirty in any XCD L2 -- r3 showed dirty lines make the 320k
// fill atomics cost ~45us in cross-XCD ownership transfers).
// Blocks 0-63 also: W (fp32) -> Wt (bf16, transposed). deg init moved to
// k_deg; cnt needs no init (k_scan writes every entry).
__global__ void k_pre(const float* __restrict__ W, unsigned short* __restrict__ Wt,
                      u4v* __restrict__ bm) {
    __shared__ unsigned short ls[4][F];
    int i = blockIdx.x * blockDim.x + threadIdx.x;

    u4v z = {0u, 0u, 0u, 0u};
    for (int b = i; b < BM_U4; b += 256 * 256)
        __builtin_nontemporal_store(z, &bm[b]);

    if (blockIdx.x < 64) {
        int n0 = blockIdx.x * 4;  // this block owns W cols n0..n0+3 (Wt rows)
        int k = threadIdx.x;
        float4 v = *(const float4*)&W[k * F + n0];
        ls[0][k] = f2bf(v.x); ls[1][k] = f2bf(v.y);
        ls[2][k] = f2bf(v.z); ls[3][k] = f2bf(v.w);
        __syncthreads();
        int nn = threadIdx.x >> 6;
        int kk = (threadIdx.x & 63) * 4;
        uint2 o;
        o.x = (unsigned)ls[nn][kk]     | ((unsigned)ls[nn][kk + 1] << 16);
        o.y = (unsigned)ls[nn][kk + 2] | ((unsigned)ls[nn][kk + 3] << 16);
        *(uint2*)&Wt[(n0 + nn) * F + kk] = o;
    }
}

// Fused fill + GEMM, block-level split (r3-proven: VGPR 64, no LDS).
// Blocks [0, FILL_BLKS): ONE fire-and-forget atomicOr per edge into the
//   (now clean-line) bitmap. Edge dtype via wave ballot: int32 -> odd words
//   are node ids (nonzero w.p. 1-1e-4); int64 -> high halves == 0.
// Blocks [FILL_BLKS, +GEMM_BLKS): H = bf16(X) @ bf16(W) via MFMA 16x16x32,
//   one wave per 16-row strip. C layout: col=lane&15, row=(lane>>4)*4+reg
//   [learn_hip m89/m91].
__global__ void __launch_bounds__(256) k_fill_gemm(
    const int* __restrict__ edges, unsigned* __restrict__ bm,
    const float* __restrict__ X, const unsigned short* __restrict__ Wt,
    unsigned short* __restrict__ H) {
    if (blockIdx.x < FILL_BLKS) {
        int probe = edges[2 * (threadIdx.x & 63) + 1];
        bool is32 = __ballot(probe != 0) != 0ull;  // wave-uniform
        int e = blockIdx.x * blockDim.x + threadIdx.x;
        if (e >= E) return;
        int s, t;
        if (is32) { s = edges[e];     t = edges[E + e]; }
        else      { s = edges[2 * e]; t = edges[2 * E + 2 * e]; }
        if ((unsigned)s >= (unsigned)N || (unsigned)t >= (unsigned)N) return;
        unsigned idx = (unsigned)s * (unsigned)(BMW * 32) + (unsigned)t;
        atomicOr(&bm[idx >> 5], 1u << (idx & 31));  // fire-and-forget
        return;
    }
    // --- GEMM path ---
    int strip = (blockIdx.x - FILL_BLKS) * 4 + (threadIdx.x >> 6);
    if (strip >= N / 16) return;
    int lane = threadIdx.x & 63;
    int r0 = strip * 16;
    int m = lane & 15, q = lane >> 4;
    const float4* A = (const float4*)(X + (r0 + m) * F + q * 8);
    const s8v* B = (const s8v*)(Wt + m * F + q * 8);
    f4v acc[16] = {};
#pragma unroll
    for (int kk = 0; kk < 8; ++kk) {
        float4 u = A[kk * 8];
        float4 v = A[kk * 8 + 1];
        s8v af;
        af[0] = (short)f2bf(u.x); af[1] = (short)f2bf(u.y);
        af[2] = (short)f2bf(u.z); af[3] = (short)f2bf(u.w);
        af[4] = (short)f2bf(v.x); af[5] = (short)f2bf(v.y);
        af[6] = (short)f2bf(v.z); af[7] = (short)f2bf(v.w);
#pragma unroll
        for (int t = 0; t < 16; ++t) {
            s8v bf = B[t * 512 + kk * 4];
            acc[t] = __builtin_amdgcn_mfma_f32_16x16x32_bf16(af, bf, acc[t], 0, 0, 0);
        }
    }
#pragma unroll
    for (int t = 0; t < 16; ++t) {
        int col = t * 16 + m;
#pragma unroll
        for (int i = 0; i < 4; ++i)
            H[(r0 + q * 4 + i) * F + col] = f2bf(acc[t][i]);
    }
}

// Bitmap scan: 157 blocks x 64 rows, 4 waves (wave w does rows w, w+4, ...).
// Per row: coalesced 5x stride-64 word loads, popcount + wave prefix (shfl)
// -> exact adj offsets and cnt (no cnt atomics). deg contributions go to a
// PRIVATE LDS histogram via ds_add (cheap), flushed NON-atomically to
// part[block][N]. Zero global atomics in this kernel.
__global__ void __launch_bounds__(256) k_scan(
    const unsigned* __restrict__ bm, int* __restrict__ adj,
    int* __restrict__ cnt, int* __restrict__ part) {
    __shared__ int hist[N];  // 40,000 B
    int tid = threadIdx.x;
    {   // zero hist: 2500 int4 / 256 thr = 10 iters
        int4 z; z.x = 0; z.y = 0; z.z = 0; z.w = 0;
        int4* h4 = (int4*)hist;
        for (int i = tid; i < N / 4; i += 256) h4[i] = z;
    }
    __syncthreads();

    int wave = tid >> 6, lane = tid & 63;
    for (int r = wave; r < SROWS; r += 4) {
        int s = blockIdx.x * SROWS + r;
        if (s >= N) break;  // wave-uniform (only last block)
        const unsigned* row = bm + (size_t)s * BMW;
        unsigned w0 = row[lane];
        unsigned w1 = row[lane + 64];
        unsigned w2 = row[lane + 128];
        unsigned w3 = row[lane + 192];
        unsigned w4 = row[lane + 256];
        int pc = __popc(w0) + __popc(w1) + __popc(w2) + __popc(w3) + __popc(w4);
        int sc = pc;
#pragma unroll
        for (int d = 1; d < 64; d <<= 1) {
            int v = __shfl_up(sc, d);
            if (lane >= d) sc += v;
        }
        int o = sc - pc;  // exclusive prefix = this lane's first adj slot
        if (lane == 63) cnt[s] = sc < DEGCAP ? sc : DEGCAP;
        int* arow = adj + s * DEGCAP;
        unsigned wv[5] = {w0, w1, w2, w3, w4};
#pragma unroll
        for (int j = 0; j < 5; ++j) {
            unsigned w = wv[j];
            int base = (j * 64 + lane) * 32;
            while (w) {
                int b = __ffs(w) - 1;
                w &= w - 1;
                int t = base + b;
                if (o < DEGCAP) arow[o] = t;
                ++o;
                atomicAdd(&hist[t], 1);  // LDS ds_add: cheap, block-private
            }
        }
    }
    __syncthreads();
    // non-atomic coalesced flush of the block's partial histogram
    int* dst = part + (size_t)blockIdx.x * N;
    int4* h4 = (int4*)hist;
    int4* d4 = (int4*)dst;
    for (int i = tid; i < N / 4; i += 256) d4[i] = h4[i];
}

// deg[j] = 1 (self-loop) + sum over 157 block partials. Reads coalesce
// across threads (part[b][j..j+63] contiguous). 6.28 MB, zero atomics.
__global__ void k_deg(const int* __restrict__ part, int* __restrict__ deg) {
    int j = blockIdx.x * blockDim.x + threadIdx.x;
    if (j >= N) return;
    int sum = 1;
#pragma unroll 4
    for (int b = 0; b < SBLKS; ++b) sum += part[(size_t)b * N + j];
    deg[j] = sum;
}

#define ACC8(hv, dv)                                          \
    p0 += dv * bf2f((unsigned short)(hv.x & 0xFFFF));         \
    p1 += dv * bf2f((unsigned short)(hv.x >> 16));            \
    p2 += dv * bf2f((unsigned short)(hv.y & 0xFFFF));         \
    p3 += dv * bf2f((unsigned short)(hv.y >> 16));            \
    p4 += dv * bf2f((unsigned short)(hv.z & 0xFFFF));         \
    p5 += dv * bf2f((unsigned short)(hv.z >> 16));            \
    p6 += dv * bf2f((unsigned short)(hv.w & 0xFFFF));         \
    p7 += dv * bf2f((unsigned short)(hv.w >> 16));

// r7/r10-proven gather, fp32 output (UNCHANGED this round -- isolate the
// atomic-elimination variables; gather is next round's target).
__global__ void k_gather(const int* __restrict__ adj, const int* __restrict__ cnt,
                         const int* __restrict__ deg,
                         const unsigned short* __restrict__ H,
                         float* __restrict__ out) {
    int wave = threadIdx.x >> 6;
    int lane = threadIdx.x & 63;
    int s = blockIdx.x * 4 + wave;  // N = 2500*4 exactly
    int half = lane >> 5, hl = lane & 31;
    const uint4* H16 = (const uint4*)H;  // 8 bf16 per uint4; row stride 32
    float ds = rsqrtf((float)deg[s]);
    int c = cnt[s]; if (c > DEGCAP) c = DEGCAP;
    const int* a = adj + s * DEGCAP;
    int tl = 0; float dl = 0.0f;
    if (lane < c) { tl = a[lane]; dl = rsqrtf((float)deg[tl]); }

    uint4 hs = H16[s * 32 + hl];
    float p0, p1, p2, p3, p4, p5, p6, p7;
    {
        float w = half ? 0.0f : ds;  // self term once (half 0 only)
        p0 = w * bf2f((unsigned short)(hs.x & 0xFFFF));
        p1 = w * bf2f((unsigned short)(hs.x >> 16));
        p2 = w * bf2f((unsigned short)(hs.y & 0xFFFF));
        p3 = w * bf2f((unsigned short)(hs.y >> 16));
        p4 = w * bf2f((unsigned short)(hs.z & 0xFFFF));
        p5 = w * bf2f((unsigned short)(hs.z >> 16));
        p6 = w * bf2f((unsigned short)(hs.w & 0xFFFF));
        p7 = w * bf2f((unsigned short)(hs.w >> 16));
    }
    int cc = c < 64 ? c : 64;
    for (int i = 0; i < cc; i += 8) {  // 4 pairs = 8 neighbors per iter
        int i0 = i + half, i1 = i + 2 + half, i2 = i + 4 + half, i3 = i + 6 + half;
        int t0 = __shfl(tl, i0), t1 = __shfl(tl, i1);
        int t2 = __shfl(tl, i2), t3 = __shfl(tl, i3);
        float d0 = __shfl(dl, i0), d1 = __shfl(dl, i1);
        float d2 = __shfl(dl, i2), d3 = __shfl(dl, i3);
        uint4 h0 = H16[t0 * 32 + hl];
        uint4 h1 = H16[t1 * 32 + hl];
        uint4 h2 = H16[t2 * 32 + hl];
        uint4 h3 = H16[t3 * 32 + hl];
        ACC8(h0, d0) ACC8(h1, d1) ACC8(h2, d2) ACC8(h3, d3)
    }
    for (int i = 64; i < c; ++i) {  // rare: deduped degree > 64
        int t = a[i];
        float d = half ? 0.0f : rsqrtf((float)deg[t]);
        uint4 h = H16[t * 32 + hl];
        ACC8(h, d)
    }
    p0 += __shfl(p0, lane ^ 32); p1 += __shfl(p1, lane ^ 32);
    p2 += __shfl(p2, lane ^ 32); p3 += __shfl(p3, lane ^ 32);
    p4 += __shfl(p4, lane ^ 32); p5 += __shfl(p5, lane ^ 32);
    p6 += __shfl(p6, lane ^ 32); p7 += __shfl(p7, lane ^ 32);
    p0 = fmaxf(p0 * ds, 0.0f); p1 = fmaxf(p1 * ds, 0.0f);
    p2 = fmaxf(p2 * ds, 0.0f); p3 = fmaxf(p3 * ds, 0.0f);
    p4 = fmaxf(p4 * ds, 0.0f); p5 = fmaxf(p5 * ds, 0.0f);
    p6 = fmaxf(p6 * ds, 0.0f); p7 = fmaxf(p7 * ds, 0.0f);
    float4 o;
    if (half) { o.x = p4; o.y = p5; o.z = p6; o.w = p7; }
    else      { o.x = p0; o.y = p1; o.z = p2; o.w = p3; }
    ((float4*)out)[s * 64 + hl * 2 + half] = o;
}

extern "C" void kernel_launch(void* const* d_in, const int* in_sizes, int n_in,
                              void* d_out, int out_size, void* d_ws, size_t ws_size,
                              hipStream_t stream) {
    const float* X = (const float*)d_in[0];
    const float* W = (const float*)d_in[1];
    const int* edges = (const int*)d_in[2];

    char* ws = (char*)d_ws;
    int* deg           = (int*)(ws + OFF_DEG);
    int* cnt           = (int*)(ws + OFF_CNT);
    int* adj           = (int*)(ws + OFF_ADJ);
    unsigned short* Wt = (unsigned short*)(ws + OFF_WT);
    unsigned short* H  = (unsigned short*)(ws + OFF_H);
    unsigned* bm       = (unsigned*)(ws + OFF_BM);
    int* part          = (int*)(ws + OFF_PART);

    k_pre<<<256, 256, 0, stream>>>(W, Wt, (u4v*)bm);
    k_fill_gemm<<<FILL_BLKS + GEMM_BLKS, 256, 0, stream>>>(edges, bm, X, Wt, H);
    k_scan<<<SBLKS, 256, 0, stream>>>(bm, adj, cnt, part);
    k_deg<<<(N + 255) / 256, 256, 0, stream>>>(part, deg);
    k_gather<<<N / 4, 256, 0, stream>>>(adj, cnt, deg, H, (float*)d_out);
}

// Round 8
// 156.419 us; speedup vs baseline: 1.1481x; 1.0785x over previous
//
#include <hip/hip_runtime.h>
#include <hip/hip_bf16.h>

// GCN layer: out = relu( D^-1/2 (dedup(A) + I) D^-1/2 (X @ W) )
// N=10000, E=320000, F=256.
// Storage: fp32 X/W/out (PROVEN r9/r10). Edges: int32 expected, int64
// tolerated via per-wave ballot detect.
// Cost model (r1/r3/r7 measured): 320k device-scope atomic RMWs scattered
// over the 12.8 MB bitmap cost ~45-50us REGARDLESS of chain structure
// (r1 51us) or line cleanliness (r7 NT-zero 50us == r3 dirty 49us).
// LDS-hist scan regressed vs plain deg atomics (r7: +15us) -- scattered
// atomics to SMALL rate-limited targets are cheap; big-region atomics are
// the poison. THIS ROUND: test the LOCALITY axis. Partition sources into
// 8 slices of 1250 rows (1.6 MB of bitmap each, fits one XCD L2).
// k_bucket_gemm routes each edge to its partition via LDS buckets +
// per-(block,partition) reserved regions (plain stores, zero global
// atomics). k_fillp assigns partition p to blocks with blockIdx%8==p
// (round-robin blockIdx->XCD on MI355X) so slice p is touched by ONE XCD
// -> atomics become XCD-local L2 RMWs. NT bitmap zero keeps slices out of
// remote L2s. Scan reverted to r2's exact version (best measured, 150us).
// 5 launches: k_pre -> k_bucket_gemm (GEMM fused at BLOCK level, r3-proven
// neutral) -> k_fillp -> k_scan -> k_gather.
// r8: no cooperative mega-kernel. r6: GEMM merge only at BLOCK level.
//
// ws layout (bytes), ~25.9 MB (ws is 256 MiB):
//   deg    i32[N]         @ 0
//   cnt    i32[N]         @ 40,960
//   adj    i32[N*96]      @ 81,920
//   Wt     bf16[F*F]      @ 3,921,920
//   H      bf16[N*F]      @ 4,052,992
//   bm     u32[N*320]     @ 9,172,992    (12.8 MB dedup bitmap, 8x1.6MB slices)
//   cntpb  i32[8*1250]    @ 21,972,992   (per-(partition,block) bucket counts)
//   region i32[8*1250*96] @ 22,012,992   (3.84 MB bucketed packed edges)

constexpr int N = 10000;
constexpr int E = 320000;
constexpr int F = 256;
constexpr int DEGCAP = 96;   // Poisson(32): P(any deduped degree >= 96) ~ 1e-16
constexpr int BMW = 320;     // bitmap words per row (10240 bits >= N)
constexpr int NPART = 8;     // partitions == XCDs
constexpr int PROWS = 1250;  // rows per partition
constexpr int RCAP = 96;     // per-(block,partition) bucket cap: Binom(256,1/8)
                             // mean 32, 96 = +12sigma, P(overflow) ~ 1e-20

constexpr size_t OFF_DEG   = 0;
constexpr size_t OFF_CNT   = 40960;
constexpr size_t OFF_ADJ   = 81920;
constexpr size_t OFF_WT    = OFF_ADJ + 4ull * N * DEGCAP;   // 3,921,920
constexpr size_t OFF_H     = OFF_WT + 2ull * F * F;         // 4,052,992
constexpr size_t OFF_BM    = OFF_H + 2ull * N * F;          // 9,172,992
constexpr size_t OFF_CNTPB = OFF_BM + 4ull * N * BMW;       // 21,972,992
constexpr size_t OFF_REG   = OFF_CNTPB + 4ull * NPART * PROWS;  // 22,012,992
constexpr int BM_U4 = N * BMW / 4;                          // 800,000

constexpr int BKT_BLKS  = (E + 255) / 256;               // 1250
constexpr int GEMM_BLKS = (N / 16 + 3) / 4;              // 157 (628 strips, 625 used)
constexpr int FP_BLKS   = 157 * NPART;                   // 1256 fillp blocks

typedef short s8v __attribute__((ext_vector_type(8)));   // 8 bf16 = 4 VGPRs
typedef float f4v __attribute__((ext_vector_type(4)));   // MFMA accumulator
typedef unsigned u4v __attribute__((ext_vector_type(4)));  // native vec for NT store

__device__ __forceinline__ float bf2f(unsigned short u) {
    union { unsigned u; float f; } c; c.u = (unsigned)u << 16; return c.f;
}
__device__ __forceinline__ unsigned short f2bf(float f) {
    union { __hip_bfloat16 b; unsigned short s; } c; c.b = __float2bfloat16(f); return c.s;
}

// 256 blocks: deg=1; cntpb=0 (10000 ints, same bound as deg); NT-zero the
// bitmap (keep slices out of all L2s so k_fillp pulls clean lines into its
// LOCAL L2). Blocks 0-63: W (fp32) -> Wt (bf16, transposed). cnt needs no
// init (k_scan writes every entry).
__global__ void k_pre(int* __restrict__ deg, int* __restrict__ cntpb,
                      const float* __restrict__ W, unsigned short* __restrict__ Wt,
                      u4v* __restrict__ bm) {
    __shared__ unsigned short ls[4][F];
    int i = blockIdx.x * blockDim.x + threadIdx.x;
    if (i < N) { deg[i] = 1; cntpb[i] = 0; }  // NPART*PROWS == N == 10000

    u4v z = {0u, 0u, 0u, 0u};
    for (int b = i; b < BM_U4; b += 256 * 256)
        __builtin_nontemporal_store(z, &bm[b]);

    if (blockIdx.x < 64) {
        int n0 = blockIdx.x * 4;  // this block owns W cols n0..n0+3 (Wt rows)
        int k = threadIdx.x;
        float4 v = *(const float4*)&W[k * F + n0];
        ls[0][k] = f2bf(v.x); ls[1][k] = f2bf(v.y);
        ls[2][k] = f2bf(v.z); ls[3][k] = f2bf(v.w);
        __syncthreads();
        int nn = threadIdx.x >> 6;
        int kk = (threadIdx.x & 63) * 4;
        uint2 o;
        o.x = (unsigned)ls[nn][kk]     | ((unsigned)ls[nn][kk + 1] << 16);
        o.y = (unsigned)ls[nn][kk + 2] | ((unsigned)ls[nn][kk + 3] << 16);
        *(uint2*)&Wt[(n0 + nn) * F + kk] = o;
    }
}

// Fused bucket + GEMM, block-level split (both depend only on k_pre).
// Blocks [0, BKT_BLKS): route 256 edges into 8 partition buckets in LDS
//   (ds_add counters, cheap), then flush each bucket to its pre-reserved
//   region[p][block][0..cnt) with plain coalesced stores + one cntpb store.
//   ZERO global atomics. Packed entry: (s - p*1250) << 14 | t  (< 2^25).
// Blocks [BKT_BLKS, +GEMM_BLKS): H = bf16(X) @ bf16(W) via MFMA 16x16x32,
//   one wave per 16-row strip (r3-proven fused pattern). C layout:
//   col=lane&15, row=(lane>>4)*4+reg [learn_hip m89/m91].
__global__ void __launch_bounds__(256) k_bucket_gemm(
    const int* __restrict__ edges, int* __restrict__ cntpb,
    int* __restrict__ region,
    const float* __restrict__ X, const unsigned short* __restrict__ Wt,
    unsigned short* __restrict__ H) {
    __shared__ int bkt[NPART][RCAP];
    __shared__ int bcnt[NPART];
    int tid = threadIdx.x;

    if (blockIdx.x < BKT_BLKS) {
        // Edge dtype probe (wave ballot): int32 -> odd words are node ids
        // (nonzero w.p. 1-1e-4); int64 -> high halves == 0 (ids < 1e4).
        int probe = edges[2 * (tid & 63) + 1];
        bool is32 = __ballot(probe != 0) != 0ull;
        if (tid < NPART) bcnt[tid] = 0;
        __syncthreads();
        int e = blockIdx.x * 256 + tid;
        if (e < E) {
            int s, t;
            if (is32) { s = edges[e];     t = edges[E + e]; }
            else      { s = edges[2 * e]; t = edges[2 * E + 2 * e]; }
            if ((unsigned)s < (unsigned)N && (unsigned)t < (unsigned)N) {
                int p = s / PROWS;  // 0..7
                int v = ((s - p * PROWS) << 14) | t;
                int pos = atomicAdd(&bcnt[p], 1);  // LDS atomic: cheap
                if (pos < RCAP) bkt[p][pos] = v;
            }
        }
        __syncthreads();
        // flush: wave w handles partitions 2w and 2w+1
        int wv = tid >> 6, ln = tid & 63;
#pragma unroll
        for (int q = 0; q < 2; ++q) {
            int p = wv * 2 + q;
            int c = bcnt[p]; if (c > RCAP) c = RCAP;
            int* dst = region + ((size_t)p * BKT_BLKS + blockIdx.x) * RCAP;
            for (int i2 = ln; i2 < c; i2 += 64) dst[i2] = bkt[p][i2];
            if (ln == 0) cntpb[p * BKT_BLKS + blockIdx.x] = c;
        }
        return;
    }
    // --- GEMM path ---
    int strip = (blockIdx.x - BKT_BLKS) * 4 + (tid >> 6);
    if (strip >= N / 16) return;
    int lane = tid & 63;
    int r0 = strip * 16;
    int m = lane & 15, q = lane >> 4;
    const float4* A = (const float4*)(X + (r0 + m) * F + q * 8);
    const s8v* B = (const s8v*)(Wt + m * F + q * 8);
    f4v acc[16] = {};
#pragma unroll
    for (int kk = 0; kk < 8; ++kk) {
        float4 u = A[kk * 8];
        float4 v = A[kk * 8 + 1];
        s8v af;
        af[0] = (short)f2bf(u.x); af[1] = (short)f2bf(u.y);
        af[2] = (short)f2bf(u.z); af[3] = (short)f2bf(u.w);
        af[4] = (short)f2bf(v.x); af[5] = (short)f2bf(v.y);
        af[6] = (short)f2bf(v.z); af[7] = (short)f2bf(v.w);
#pragma unroll
        for (int t = 0; t < 16; ++t) {
            s8v bf = B[t * 512 + kk * 4];
            acc[t] = __builtin_amdgcn_mfma_f32_16x16x32_bf16(af, bf, acc[t], 0, 0, 0);
        }
    }
#pragma unroll
    for (int t = 0; t < 16; ++t) {
        int col = t * 16 + m;
#pragma unroll
        for (int i = 0; i < 4; ++i)
            H[(r0 + q * 4 + i) * F + col] = f2bf(acc[t][i]);
    }
}

// Partition-local bitmap fill: block b serves partition p = b%8 (same-p
// blocks are 8 apart -> same XCD under round-robin dispatch). Each block
// drains 8 source-block buckets of its partition; all atomics land in the
// partition's contiguous 1.6 MB bitmap slice -> XCD-local L2 RMWs.
// Duplicate (s,t) across buckets -> same bit, idempotent.
__global__ void __launch_bounds__(256) k_fillp(
    const int* __restrict__ cntpb, const int* __restrict__ region,
    unsigned* __restrict__ bm) {
    int p = blockIdx.x & 7;
    int g = blockIdx.x >> 3;  // 0..156
    int tid = threadIdx.x;
    unsigned rowbase = (unsigned)p * PROWS;
#pragma unroll
    for (int jj = 0; jj < 8; ++jj) {
        int j = g * 8 + jj;
        if (j >= BKT_BLKS) break;
        int c = cntpb[p * BKT_BLKS + j];
        const int* src = region + ((size_t)p * BKT_BLKS + j) * RCAP;
        for (int i = tid; i < c; i += 256) {
            int v = src[i];
            unsigned row = rowbase + (unsigned)(v >> 14);
            unsigned t = (unsigned)(v & 16383);
            unsigned idx = row * (unsigned)(BMW * 32) + t;
            atomicOr(&bm[idx >> 5], 1u << (idx & 31));  // fire-and-forget, local slice
        }
    }
}

// Bitmap scan (r2 EXACT -- best measured structure): one wave per node row
// (2500 blocks x 4 waves). Coalesced 5x stride-64 word loads, popcount +
// wave prefix (shfl) -> exact adj offsets and cnt (no cnt atomics).
// deg[t]++ fire-and-forget (dense 40KB target; r7 proved LDS-hist is WORSE).
__global__ void k_scan(const unsigned* __restrict__ bm, int* __restrict__ adj,
                       int* __restrict__ cnt, int* __restrict__ deg) {
    int wave = threadIdx.x >> 6, lane = threadIdx.x & 63;
    int s = blockIdx.x * 4 + wave;  // N = 2500*4 exactly
    const unsigned* row = bm + (size_t)s * BMW;
    unsigned w0 = row[lane];
    unsigned w1 = row[lane + 64];
    unsigned w2 = row[lane + 128];
    unsigned w3 = row[lane + 192];
    unsigned w4 = row[lane + 256];
    int pc = __popc(w0) + __popc(w1) + __popc(w2) + __popc(w3) + __popc(w4);
    int sc = pc;
#pragma unroll
    for (int d = 1; d < 64; d <<= 1) {
        int v = __shfl_up(sc, d);
        if (lane >= d) sc += v;
    }
    int o = sc - pc;  // exclusive prefix = this lane's first adj slot
    if (lane == 63) cnt[s] = sc < DEGCAP ? sc : DEGCAP;
    int* arow = adj + s * DEGCAP;
    unsigned wv[5] = {w0, w1, w2, w3, w4};
#pragma unroll
    for (int j = 0; j < 5; ++j) {
        unsigned w = wv[j];
        int base = (j * 64 + lane) * 32;
        while (w) {
            int b = __ffs(w) - 1;
            w &= w - 1;
            int t = base + b;
            if (o < DEGCAP) arow[o] = t;
            ++o;
            atomicAdd(&deg[t], 1);  // fire-and-forget, dense target
        }
    }
}

#define ACC8(hv, dv)                                          \
    p0 += dv * bf2f((unsigned short)(hv.x & 0xFFFF));         \
    p1 += dv * bf2f((unsigned short)(hv.x >> 16));            \
    p2 += dv * bf2f((unsigned short)(hv.y & 0xFFFF));         \
    p3 += dv * bf2f((unsigned short)(hv.y >> 16));            \
    p4 += dv * bf2f((unsigned short)(hv.z & 0xFFFF));         \
    p5 += dv * bf2f((unsigned short)(hv.z >> 16));            \
    p6 += dv * bf2f((unsigned short)(hv.w & 0xFFFF));         \
    p7 += dv * bf2f((unsigned short)(hv.w >> 16));

// r7/r10-proven gather, fp32 output (UNCHANGED -- isolate fill variables).
__global__ void k_gather(const int* __restrict__ adj, const int* __restrict__ cnt,
                         const int* __restrict__ deg,
                         const unsigned short* __restrict__ H,
                         float* __restrict__ out) {
    int wave = threadIdx.x >> 6;
    int lane = threadIdx.x & 63;
    int s = blockIdx.x * 4 + wave;  // N = 2500*4 exactly
    int half = lane >> 5, hl = lane & 31;
    const uint4* H16 = (const uint4*)H;  // 8 bf16 per uint4; row stride 32
    float ds = rsqrtf((float)deg[s]);
    int c = cnt[s]; if (c > DEGCAP) c = DEGCAP;
    const int* a = adj + s * DEGCAP;
    int tl = 0; float dl = 0.0f;
    if (lane < c) { tl = a[lane]; dl = rsqrtf((float)deg[tl]); }

    uint4 hs = H16[s * 32 + hl];
    float p0, p1, p2, p3, p4, p5, p6, p7;
    {
        float w = half ? 0.0f : ds;  // self term once (half 0 only)
        p0 = w * bf2f((unsigned short)(hs.x & 0xFFFF));
        p1 = w * bf2f((unsigned short)(hs.x >> 16));
        p2 = w * bf2f((unsigned short)(hs.y & 0xFFFF));
        p3 = w * bf2f((unsigned short)(hs.y >> 16));
        p4 = w * bf2f((unsigned short)(hs.z & 0xFFFF));
        p5 = w * bf2f((unsigned short)(hs.z >> 16));
        p6 = w * bf2f((unsigned short)(hs.w & 0xFFFF));
        p7 = w * bf2f((unsigned short)(hs.w >> 16));
    }
    int cc = c < 64 ? c : 64;
    for (int i = 0; i < cc; i += 8) {  // 4 pairs = 8 neighbors per iter
        int i0 = i + half, i1 = i + 2 + half, i2 = i + 4 + half, i3 = i + 6 + half;
        int t0 = __shfl(tl, i0), t1 = __shfl(tl, i1);
        int t2 = __shfl(tl, i2), t3 = __shfl(tl, i3);
        float d0 = __shfl(dl, i0), d1 = __shfl(dl, i1);
        float d2 = __shfl(dl, i2), d3 = __shfl(dl, i3);
        uint4 h0 = H16[t0 * 32 + hl];
        uint4 h1 = H16[t1 * 32 + hl];
        uint4 h2 = H16[t2 * 32 + hl];
        uint4 h3 = H16[t3 * 32 + hl];
        ACC8(h0, d0) ACC8(h1, d1) ACC8(h2, d2) ACC8(h3, d3)
    }
    for (int i = 64; i < c; ++i) {  // rare: deduped degree > 64
        int t = a[i];
        float d = half ? 0.0f : rsqrtf((float)deg[t]);
        uint4 h = H16[t * 32 + hl];
        ACC8(h, d)
    }
    p0 += __shfl(p0, lane ^ 32); p1 += __shfl(p1, lane ^ 32);
    p2 += __shfl(p2, lane ^ 32); p3 += __shfl(p3, lane ^ 32);
    p4 += __shfl(p4, lane ^ 32); p5 += __shfl(p5, lane ^ 32);
    p6 += __shfl(p6, lane ^ 32); p7 += __shfl(p7, lane ^ 32);
    p0 = fmaxf(p0 * ds, 0.0f); p1 = fmaxf(p1 * ds, 0.0f);
    p2 = fmaxf(p2 * ds, 0.0f); p3 = fmaxf(p3 * ds, 0.0f);
    p4 = fmaxf(p4 * ds, 0.0f); p5 = fmaxf(p5 * ds, 0.0f);
    p6 = fmaxf(p6 * ds, 0.0f); p7 = fmaxf(p7 * ds, 0.0f);
    float4 o;
    if (half) { o.x = p4; o.y = p5; o.z = p6; o.w = p7; }
    else      { o.x = p0; o.y = p1; o.z = p2; o.w = p3; }
    ((float4*)out)[s * 64 + hl * 2 + half] = o;
}

extern "C" void kernel_launch(void* const* d_in, const int* in_sizes, int n_in,
                              void* d_out, int out_size, void* d_ws, size_t ws_size,
                              hipStream_t stream) {
    const float* X = (const float*)d_in[0];
    const float* W = (const float*)d_in[1];
    const int* edges = (const int*)d_in[2];

    char* ws = (char*)d_ws;
    int* deg           = (int*)(ws + OFF_DEG);
    int* cnt           = (int*)(ws + OFF_CNT);
    int* adj           = (int*)(ws + OFF_ADJ);
    unsigned short* Wt = (unsigned short*)(ws + OFF_WT);
    unsigned short* H  = (unsigned short*)(ws + OFF_H);
    unsigned* bm       = (unsigned*)(ws + OFF_BM);
    int* cntpb         = (int*)(ws + OFF_CNTPB);
    int* region        = (int*)(ws + OFF_REG);

    k_pre<<<256, 256, 0, stream>>>(deg, cntpb, W, Wt, (u4v*)bm);
    k_bucket_gemm<<<BKT_BLKS + GEMM_BLKS, 256, 0, stream>>>(edges, cntpb, region, X, Wt, H);
    k_fillp<<<FP_BLKS, 256, 0, stream>>>(cntpb, region, bm);
    k_scan<<<N / 4, 256, 0, stream>>>(bm, adj, cnt, deg);
    k_gather<<<N / 4, 256, 0, stream>>>(adj, cnt, deg, H, (float*)d_out);
}